// Round 3
// baseline (1076.301 us; speedup 1.0000x reference)
//
#include <hip/hip_runtime.h>

// EquivLayerNorm fused kernel for MI355X.
// Math (exact algebraic collapse of the reference):
//   gmean = segmean_n( mean_j s[n,j] )
//   gvar  = max( segmean_n( mean_j s^2 ) - gmean^2 , EPS )
//   sout  = (s - gmean) / gvar * w + b
//   gvm   = max( segmean_n( sum_{axis,d} v^2 ) / 64 , EPS )
//   vout  = v / gvm
// batch is SORTED -> each segment is a contiguous node range. One block per
// graph (grid-strided); phase 1 reduces stats, phase 2 re-reads (L3-hot) and
// normalizes. grid=256 (1 block/CU) keeps the live working set (~160 MB)
// under the 256 MB Infinity Cache so phase-2 re-reads hit L3. Nontemporal
// stores keep outputs from polluting L2/L3; phase-2 loads are PLAIN loads
// (nt-load replacement semantics on gfx950 are unverified and could defeat
// the L3 hit we rely on).

#define MAIN_THREADS 1024
#define MAIN_GRID 256
#define EPS 1e-6f

typedef float vfloat4 __attribute__((ext_vector_type(4)));

__device__ __forceinline__ int lower_bound_i(const int* __restrict__ a, int n, int val) {
    int lo = 0, hi = n;
    while (lo < hi) {
        int mid = (lo + hi) >> 1;
        if (a[mid] < val) lo = mid + 1; else hi = mid;
    }
    return lo;
}

__device__ __forceinline__ void nt_store4(float4* p, float4 x) {
    vfloat4 r; r.x = x.x; r.y = x.y; r.z = x.z; r.w = x.w;
    __builtin_nontemporal_store(r, reinterpret_cast<vfloat4*>(p));
}

// Precompute segment boundaries into ws: off[g] = first node index of graph g,
// for g in [0, Beff], off[Beff] = N. Guarded by capB (ws capacity in ints - 1).
__global__ void eln_boundaries(const int* __restrict__ batch, int N,
                               int* __restrict__ off, int capB) {
    const int Beff = batch[N - 1] + 1;
    const int stride = gridDim.x * blockDim.x;
    for (int g = blockIdx.x * blockDim.x + threadIdx.x; g <= Beff; g += stride) {
        if (g <= capB) off[g] = lower_bound_i(batch, N, g);
    }
}

__global__ __launch_bounds__(MAIN_THREADS) void eln_fused(
    const float* __restrict__ s, const float* __restrict__ v,
    const float* __restrict__ wgt, const float* __restrict__ bia,
    const int* __restrict__ batch, const int* __restrict__ off, int capB,
    float* __restrict__ souts, float* __restrict__ vouts, int N)
{
    const int Beff = batch[N - 1] + 1;
    const bool use_off = (off != nullptr) && (Beff <= capB);

    __shared__ float red[MAIN_THREADS / 64][3];
    __shared__ float stats[3];

    const int tid  = threadIdx.x;
    const int lane = tid & 63;
    const int wid  = tid >> 6;

    const float4* s4 = reinterpret_cast<const float4*>(s);
    const float4* v4 = reinterpret_cast<const float4*>(v);
    float4* so4 = reinterpret_cast<float4*>(souts);
    float4* vo4 = reinterpret_cast<float4*>(vouts);

    // Row length 128 f32 = 32 float4; stride MAIN_THREADS % 32 == 0
    // => thread t always touches column-block (t & 31) of s.
    const float4 w4 = reinterpret_cast<const float4*>(wgt)[tid & 31];
    const float4 b4 = reinterpret_cast<const float4*>(bia)[tid & 31];

    for (int g = blockIdx.x; g < Beff; g += gridDim.x) {
        int start, end;
        if (use_off) {
            start = off[g];
            end   = off[g + 1];
        } else {
            start = lower_bound_i(batch, N, g);
            end   = lower_bound_i(batch, N, g + 1);
        }
        const int cnt = end - start;

        // ---- phase 1: stats (HBM-streaming read; lines land in L2/L3) ----
        float sum_s = 0.f, sum_s2 = 0.f, sum_v2 = 0.f;
        const int s_lo = start * 32 + tid, s_hi = end * 32;   // float4 indices
        const int v_lo = start * 48 + tid, v_hi = end * 48;
        #pragma unroll 8
        for (int i = s_lo; i < s_hi; i += MAIN_THREADS) {
            float4 x = s4[i];
            sum_s  += (x.x + x.y) + (x.z + x.w);
            sum_s2 += x.x * x.x + x.y * x.y + x.z * x.z + x.w * x.w;
        }
        #pragma unroll 8
        for (int i = v_lo; i < v_hi; i += MAIN_THREADS) {
            float4 x = v4[i];
            sum_v2 += x.x * x.x + x.y * x.y + x.z * x.z + x.w * x.w;
        }
        #pragma unroll
        for (int o = 32; o > 0; o >>= 1) {
            sum_s  += __shfl_down(sum_s,  o, 64);
            sum_s2 += __shfl_down(sum_s2, o, 64);
            sum_v2 += __shfl_down(sum_v2, o, 64);
        }
        if (lane == 0) {
            red[wid][0] = sum_s; red[wid][1] = sum_s2; red[wid][2] = sum_v2;
        }
        __syncthreads();
        if (tid == 0) {
            float ts = 0.f, ts2 = 0.f, tv2 = 0.f;
            #pragma unroll
            for (int w = 0; w < MAIN_THREADS / 64; ++w) {
                ts += red[w][0]; ts2 += red[w][1]; tv2 += red[w][2];
            }
            const float fc    = fmaxf((float)cnt, 1.0f);
            const float invns = 1.0f / (128.0f * fc);
            const float gmean = ts * invns;
            const float gvar  = fmaxf(ts2 * invns - gmean * gmean, EPS);
            const float gvm   = fmaxf(tv2 / (64.0f * fc), EPS);
            stats[0] = gmean;
            stats[1] = 1.0f / gvar;
            stats[2] = 1.0f / gvm;
        }
        __syncthreads();
        const float gmean = stats[0], ivar = stats[1], ivm = stats[2];

        // ---- phase 2: normalize + write (reads should hit L2/L3) ----
        #pragma unroll 4
        for (int i = s_lo; i < s_hi; i += MAIN_THREADS) {
            float4 x = s4[i];
            float4 o;
            o.x = (x.x - gmean) * ivar * w4.x + b4.x;
            o.y = (x.y - gmean) * ivar * w4.y + b4.y;
            o.z = (x.z - gmean) * ivar * w4.z + b4.z;
            o.w = (x.w - gmean) * ivar * w4.w + b4.w;
            nt_store4(&so4[i], o);
        }
        #pragma unroll 4
        for (int i = v_lo; i < v_hi; i += MAIN_THREADS) {
            float4 x = v4[i];
            float4 o;
            o.x = x.x * ivm; o.y = x.y * ivm; o.z = x.z * ivm; o.w = x.w * ivm;
            nt_store4(&vo4[i], o);
        }
        // No trailing barrier needed: next iteration's barriers order red/stats
        // reuse (all reads of red/stats precede the writes that follow them).
    }
}

extern "C" void kernel_launch(void* const* d_in, const int* in_sizes, int n_in,
                              void* d_out, int out_size, void* d_ws, size_t ws_size,
                              hipStream_t stream) {
    const float* s   = (const float*)d_in[0];
    const float* v   = (const float*)d_in[1];
    const float* wgt = (const float*)d_in[2];
    const float* bia = (const float*)d_in[3];
    const int*   bat = (const int*)d_in[4];
    const int N = in_sizes[4];

    float* souts = (float*)d_out;
    float* vouts = souts + (size_t)N * 128;

    // Segment-offset table in workspace if it fits (needs (Beff+1)*4 bytes;
    // Beff <= 1024 in this problem). Fallback: in-kernel binary search.
    int* off = nullptr;
    int capB = -1;
    if (ws_size >= 4 * 4200) {
        off  = (int*)d_ws;
        capB = (int)(ws_size / 4) - 2;
        if (capB > 1 << 20) capB = 1 << 20;
        eln_boundaries<<<16, 256, 0, stream>>>(bat, N, off, capB);
    }

    eln_fused<<<MAIN_GRID, MAIN_THREADS, 0, stream>>>(
        s, v, wgt, bia, bat, off, capB, souts, vouts, N);
}